// Round 7
// baseline (1112.698 us; speedup 1.0000x reference)
//
#include <hip/hip_runtime.h>

#define BN_EPS 1e-5f

typedef __attribute__((ext_vector_type(8))) short short8;
typedef __attribute__((ext_vector_type(4))) float floatx4;

#define GLL(gp, lp)                                                            \
    __builtin_amdgcn_global_load_lds(                                          \
        (const __attribute__((address_space(1))) void*)(gp),                   \
        (__attribute__((address_space(3))) void*)(lp), 16, 0, 0)

__device__ inline unsigned short f2bf(float f) {
    unsigned int u = __float_as_uint(f);
    unsigned int r = (u + 0x7FFF + ((u >> 16) & 1)) >> 16;  // RNE
    return (unsigned short)r;
}

__device__ inline float bf2f(unsigned short u) {
    return __uint_as_float(((unsigned int)u) << 16);
}

// Grid barrier: 1 RMW per block (arrival), last arriver sets flag (release),
// waiters spin on acquire LOADS (no RMW contention). bar[0]=arrive, bar[1]=flag,
// both pre-zeroed each launch.
__device__ inline void grid_bar(int* bar, int nb) {
    __syncthreads();
    if (threadIdx.x == 0) {
        int old = __hip_atomic_fetch_add(&bar[0], 1, __ATOMIC_ACQ_REL, __HIP_MEMORY_SCOPE_AGENT);
        if (old == nb - 1) {
            __hip_atomic_store(&bar[1], 1, __ATOMIC_RELEASE, __HIP_MEMORY_SCOPE_AGENT);
        } else {
            while (!__hip_atomic_load(&bar[1], __ATOMIC_ACQUIRE, __HIP_MEMORY_SCOPE_AGENT))
                __builtin_amdgcn_s_sleep(16);
        }
    }
    __syncthreads();
}

// ---------------- fused CSR construction (1 kernel, 3 barriers) --------------
// grid = 256 blocks x 256 threads, co-resident. cnt pre-zeroed by host memset.

__global__ __launch_bounds__(256) void setup_kernel(
    const int* __restrict__ row, const int* __restrict__ col,
    int* __restrict__ cnt, float* __restrict__ dis,
    int* __restrict__ rowptr, int* __restrict__ cursor, int* __restrict__ adj,
    int* __restrict__ bsum, int* __restrict__ ctrs, int N, int E) {
    int b = blockIdx.x, t = threadIdx.x, nb = gridDim.x;
    int gid = b * 256 + t, gsz = nb * 256;

    // P1: count in-degree
    for (int e = gid; e < E; e += gsz) atomicAdd(&cnt[col[e]], 1);
    grid_bar(ctrs + 0, nb);

    // P2: dis + block-local inclusive scan of this block's node segment
    for (int i = gid; i < N; i += gsz) dis[i] = rsqrtf((float)(cnt[i] + 1));
    int per = (N + nb - 1) / nb;     // 40 for N=10000, nb=256
    int s0 = b * per;
    __shared__ int sc[256];
    __shared__ int sb[256];
    int v = (t < per && s0 + t < N) ? cnt[s0 + t] : 0;
    sc[t] = v;
    __syncthreads();
    for (int o = 1; o < 256; o <<= 1) {
        int u = (t >= o) ? sc[t - o] : 0;
        __syncthreads();
        sc[t] += u;
        __syncthreads();
    }
    if (t == 255) bsum[b] = sc[255];
    grid_bar(ctrs + 2, nb);

    // P3: every block redundantly scans the 256 block sums; write rowptr/cursor
    sb[t] = bsum[t];
    __syncthreads();
    for (int o = 1; o < 256; o <<= 1) {
        int u = (t >= o) ? sb[t - o] : 0;
        __syncthreads();
        sb[t] += u;
        __syncthreads();
    }
    int boff = (b == 0) ? 0 : sb[b - 1];
    if (t < per && s0 + t < N) {
        int ex = boff + sc[t] - v;
        rowptr[s0 + t] = ex;
        cursor[s0 + t] = ex;
    }
    if (b == 0 && t == 0) rowptr[N] = sb[255];
    grid_bar(ctrs + 4, nb);

    // P4: scatter edges into CSR
    for (int e = gid; e < E; e += gsz) {
        int pos = atomicAdd(&cursor[col[e]], 1);
        adj[pos] = row[e];
    }
}

// ---------------- fused fp32 -> bf16 conversion (x, W1, W2) ----------------

__global__ void f2b_all_kernel(const float* __restrict__ x, const float* __restrict__ W1,
                               const float* __restrict__ W2, ushort* __restrict__ xbf,
                               ushort* __restrict__ W1bf, ushort* __restrict__ W2bf,
                               int n4x, int n4w) {
    int i = blockIdx.x * blockDim.x + threadIdx.x;
    const float* src;
    ushort* dst;
    int j;
    if (i < n4x) { src = x; dst = xbf; j = i; }
    else if (i < n4x + n4w) { src = W1; dst = W1bf; j = i - n4x; }
    else if (i < n4x + 2 * n4w) { src = W2; dst = W2bf; j = i - n4x - n4w; }
    else return;
    float4 v = ((const float4*)src)[j];
    ushort4 o;
    o.x = f2bf(v.x); o.y = f2bf(v.y); o.z = f2bf(v.z); o.w = f2bf(v.w);
    ((ushort4*)dst)[j] = o;
}

// ---------------- MFMA GEMM: C[M,N] = A[M,K] @ B[N,K]^T (bf16 in) ----------

template <bool OUT_BF16>
__global__ __launch_bounds__(256) void gemm_mfma_kernel(
    const ushort* __restrict__ A, const ushort* __restrict__ B,
    void* __restrict__ Cout, int M, int N, int K) {
    __shared__ ushort As[128 * 32];
    __shared__ ushort Bs[128 * 32];
    int tid = threadIdx.x;
    int wave = tid >> 6;
    int lane = tid & 63;
    int quad = lane >> 4;
    int l15 = lane & 15;
    int m0 = blockIdx.y * 128;
    int n0 = blockIdx.x * 128;

    int srow = lane >> 2;
    int skoff = (lane & 3) * 8;

    floatx4 acc[4][4];
#pragma unroll
    for (int i = 0; i < 4; i++)
#pragma unroll
        for (int j = 0; j < 4; j++) acc[i][j] = (floatx4){0.f, 0.f, 0.f, 0.f};

    int wm = (wave & 1) * 64;
    int wn = (wave >> 1) * 64;

    for (int k0 = 0; k0 < K; k0 += 32) {
#pragma unroll
        for (int cc = 0; cc < 2; cc++) {
            int c = wave * 2 + cc;
            int arow = m0 + c * 16 + srow;
            arow = min(arow, M - 1);
            const ushort* ga = A + (size_t)arow * K + k0 + skoff;
            GLL(ga, (char*)As + c * 1024);
            int brow = n0 + c * 16 + srow;
            const ushort* gb = B + (size_t)brow * K + k0 + skoff;
            GLL(gb, (char*)Bs + c * 1024);
        }
        __syncthreads();

        short8 af[4], bfr[4];
#pragma unroll
        for (int i = 0; i < 4; i++) {
            int r = wm + i * 16 + l15;
            af[i] = *(const short8*)(As + r * 32 + quad * 8);
        }
#pragma unroll
        for (int j = 0; j < 4; j++) {
            int r = wn + j * 16 + l15;
            bfr[j] = *(const short8*)(Bs + r * 32 + quad * 8);
        }
#pragma unroll
        for (int i = 0; i < 4; i++)
#pragma unroll
            for (int j = 0; j < 4; j++)
                acc[i][j] = __builtin_amdgcn_mfma_f32_16x16x32_bf16(af[i], bfr[j], acc[i][j], 0, 0, 0);
        __syncthreads();
    }

#pragma unroll
    for (int i = 0; i < 4; i++) {
#pragma unroll
        for (int r = 0; r < 4; r++) {
            int row = m0 + wm + i * 16 + quad * 4 + r;
            if (row < M) {
                if (OUT_BF16) {
                    ushort* cp = (ushort*)Cout + (size_t)row * N + n0 + wn + l15;
#pragma unroll
                    for (int j = 0; j < 4; j++) cp[j * 16] = f2bf(acc[i][j][r]);
                } else {
                    float* cp = (float*)Cout + (size_t)row * N + n0 + wn + l15;
#pragma unroll
                    for (int j = 0; j < 4; j++) cp[j * 16] = acc[i][j][r];
                }
            }
        }
    }
}

// ---------------- bf16 gather, C=256 channels ----------------

template <bool OUT_BF16>
__global__ __launch_bounds__(256) void gather_bf_kernel(
    const ushort* __restrict__ xl, const int* __restrict__ rowptr,
    const int* __restrict__ adj, const float* __restrict__ dis,
    void* __restrict__ h) {
    int v = blockIdx.x;
    int wave = threadIdx.x >> 6;
    int lane = threadIdx.x & 63;
    float dv = dis[v];

    float acc[4] = {0.f, 0.f, 0.f, 0.f};
    int e0 = rowptr[v], e1 = rowptr[v + 1];
    for (int e = e0 + wave; e < e1; e += 4) {
        int r = adj[e];
        float wgt = dis[r] * dv;
        ushort4 u = ((const ushort4*)xl)[(size_t)r * 64 + lane];
        acc[0] = fmaf(bf2f(u.x), wgt, acc[0]);
        acc[1] = fmaf(bf2f(u.y), wgt, acc[1]);
        acc[2] = fmaf(bf2f(u.z), wgt, acc[2]);
        acc[3] = fmaf(bf2f(u.w), wgt, acc[3]);
    }

    __shared__ float4 red[4][64];
    red[wave][lane] = make_float4(acc[0], acc[1], acc[2], acc[3]);
    __syncthreads();
    if (wave == 0) {
        float4 s = red[0][lane];
        float4 b = red[1][lane];
        float4 c = red[2][lane];
        float4 d = red[3][lane];
        s.x += b.x + c.x + d.x;
        s.y += b.y + c.y + d.y;
        s.z += b.z + c.z + d.z;
        s.w += b.w + c.w + d.w;
        ushort4 u = ((const ushort4*)xl)[(size_t)v * 64 + lane];
        float w2 = dv * dv;
        s.x = fmaf(bf2f(u.x), w2, s.x);
        s.y = fmaf(bf2f(u.y), w2, s.y);
        s.z = fmaf(bf2f(u.z), w2, s.z);
        s.w = fmaf(bf2f(u.w), w2, s.w);
        if (OUT_BF16) {
            ushort4 o;
            o.x = f2bf(s.x); o.y = f2bf(s.y); o.z = f2bf(s.z); o.w = f2bf(s.w);
            ((ushort4*)h)[(size_t)v * 64 + lane] = o;
        } else {
            ((float4*)h)[(size_t)v * 64 + lane] = s;
        }
    }
}

// ---------------- fused BN: partials -> last-block reduce -> apply ----------
// psum/psumsq layout: [block][IC] (block-major, float4-coalesced writes).
// MODE 0: obf = bf16(relu(bn(h)));  MODE 1: fout = relu(bn(h) + xres).

template <int MODE>
__global__ __launch_bounds__(256) void bn_fused_kernel(
    const float* __restrict__ h, const float* __restrict__ gamma,
    const float* __restrict__ beta, float* __restrict__ psum,
    float* __restrict__ psumsq, float* __restrict__ scale,
    float* __restrict__ shift, ushort* __restrict__ obf,
    const float* __restrict__ xres, float* __restrict__ fout,
    int* __restrict__ ctrs, int N, int IC) {
    int nb = gridDim.x;
    int b = blockIdx.x, t = threadIdx.x;
    int groups = IC >> 2;           // 128 or 64
    int rpi = 256 / groups;
    int g = t & (groups - 1);
    int ro = t / groups;
    int per = (N + nb - 1) / nb;
    int r0 = b * per;
    int r1 = min(r0 + per, N);

    // Phase A: per-block partials
    float4 s = make_float4(0.f, 0.f, 0.f, 0.f);
    float4 q = make_float4(0.f, 0.f, 0.f, 0.f);
    for (int r = r0 + ro; r < r1; r += rpi) {
        float4 v = *(const float4*)(h + (size_t)r * IC + g * 4);
        s.x += v.x; s.y += v.y; s.z += v.z; s.w += v.w;
        q.x += v.x * v.x; q.y += v.y * v.y; q.z += v.z * v.z; q.w += v.w * v.w;
    }
    {
        __shared__ float4 redS[256];
        __shared__ float4 redQ[256];
        redS[t] = s;
        redQ[t] = q;
        __syncthreads();
        if (ro == 0) {
            for (int i = 1; i < rpi; i++) {
                float4 o = redS[t + i * groups];
                s.x += o.x; s.y += o.y; s.z += o.z; s.w += o.w;
                float4 p = redQ[t + i * groups];
                q.x += p.x; q.y += p.y; q.z += p.z; q.w += p.w;
            }
            ((float4*)(psum + (size_t)b * IC))[g] = s;
            ((float4*)(psumsq + (size_t)b * IC))[g] = q;
        }
    }

    // Arrival; last block reduces all channels, sets flag; others spin (loads).
    __shared__ int islast;
    __syncthreads();
    if (t == 0) {
        int old = __hip_atomic_fetch_add(&ctrs[0], 1, __ATOMIC_ACQ_REL, __HIP_MEMORY_SCOPE_AGENT);
        islast = (old == nb - 1);
    }
    __syncthreads();
    if (islast) {
        for (int c = t; c < IC; c += 256) {
            float ss = 0.f, qq = 0.f;
            for (int k = 0; k < nb; k++) {
                ss += psum[(size_t)k * IC + c];
                qq += psumsq[(size_t)k * IC + c];
            }
            float invN = 1.0f / (float)N;
            float mean = ss * invN;
            float var = qq * invN - mean * mean;
            float sc = gamma[c] * rsqrtf(var + BN_EPS);
            scale[c] = sc;
            shift[c] = beta[c] - mean * sc;
        }
        __syncthreads();
        if (t == 0)
            __hip_atomic_store(&ctrs[1], 1, __ATOMIC_RELEASE, __HIP_MEMORY_SCOPE_AGENT);
    } else {
        if (t == 0) {
            while (!__hip_atomic_load(&ctrs[1], __ATOMIC_ACQUIRE, __HIP_MEMORY_SCOPE_AGENT))
                __builtin_amdgcn_s_sleep(16);
        }
        __syncthreads();
    }

    // Phase C: elementwise tail (grid-stride)
    int total4 = (N * IC) / 4;
    int gid = b * 256 + t, gsz = nb * 256;
    int IC4 = IC >> 2;
    for (int i = gid; i < total4; i += gsz) {
        int c4 = (i & (IC4 - 1)) * 4;
        float4 v = ((const float4*)h)[i];
        if (MODE == 0) {
            ushort4 o;
            o.x = f2bf(fmaxf(fmaf(v.x, scale[c4 + 0], shift[c4 + 0]), 0.f));
            o.y = f2bf(fmaxf(fmaf(v.y, scale[c4 + 1], shift[c4 + 1]), 0.f));
            o.z = f2bf(fmaxf(fmaf(v.z, scale[c4 + 2], shift[c4 + 2]), 0.f));
            o.w = f2bf(fmaxf(fmaf(v.w, scale[c4 + 3], shift[c4 + 3]), 0.f));
            ((ushort4*)obf)[i] = o;
        } else {
            float4 xv = ((const float4*)xres)[i];
            float4 o;
            o.x = fmaxf(fmaf(v.x, scale[c4 + 0], shift[c4 + 0]) + xv.x, 0.f);
            o.y = fmaxf(fmaf(v.y, scale[c4 + 1], shift[c4 + 1]) + xv.y, 0.f);
            o.z = fmaxf(fmaf(v.z, scale[c4 + 2], shift[c4 + 2]) + xv.z, 0.f);
            o.w = fmaxf(fmaf(v.w, scale[c4 + 3], shift[c4 + 3]) + xv.w, 0.f);
            ((float4*)fout)[i] = o;
        }
    }
}

// ---------------- launch ----------------

extern "C" void kernel_launch(void* const* d_in, const int* in_sizes, int n_in,
                              void* d_out, int out_size, void* d_ws, size_t ws_size,
                              hipStream_t stream) {
    const float* x  = (const float*)d_in[0];
    const int*   es = (const int*)d_in[1];
    const float* W1 = (const float*)d_in[2];
    const float* g1 = (const float*)d_in[3];
    const float* b1 = (const float*)d_in[4];
    const float* W2 = (const float*)d_in[5];
    const float* g2 = (const float*)d_in[6];
    const float* b2 = (const float*)d_in[7];
    float* out = (float*)d_out;

    const int E  = in_sizes[1] / 2;
    const int IC = in_sizes[3];   // 512
    const int C  = in_sizes[7];   // 256
    const int N  = in_sizes[0] / C;
    const int NB = 256;

    const int* row = es;
    const int* col = es + E;

    // ---- workspace layout (ctrs + cnt first: one covering memset) ----
    char* w = (char*)d_ws;
    size_t off = 0;
    auto alloc = [&](size_t bytes) -> void* {
        void* p = w + off;
        off = (off + bytes + 255) & ~(size_t)255;
        return p;
    };
    int*   ctrs    = (int*)alloc(64 * 4);                     // barrier slots (256 B)
    int*   cnt     = (int*)alloc((size_t)N * 4);
    float* dis     = (float*)alloc((size_t)N * 4);
    int*   rowptr  = (int*)alloc((size_t)(N + 1) * 4);
    int*   cursor  = (int*)alloc((size_t)N * 4);
    int*   adj     = (int*)alloc((size_t)E * 4);
    int*   bsum    = (int*)alloc((size_t)NB * 4);
    float* psum    = (float*)alloc((size_t)NB * IC * 4);
    float* psumsq  = (float*)alloc((size_t)NB * IC * 4);
    float* scale1  = (float*)alloc((size_t)IC * 4);
    float* shift1  = (float*)alloc((size_t)IC * 4);
    float* scale2  = (float*)alloc((size_t)C * 4);
    float* shift2  = (float*)alloc((size_t)C * 4);
    ushort* xbf    = (ushort*)alloc((size_t)N * C * 2);
    ushort* W1bf   = (ushort*)alloc((size_t)IC * C * 2);
    ushort* W2bf   = (ushort*)alloc((size_t)IC * C * 2);
    ushort* g1x    = (ushort*)alloc((size_t)N * C * 2);
    float*  h1     = (float*)alloc((size_t)N * IC * 4);
    ushort* h1bf   = (ushort*)alloc((size_t)N * IC * 2);
    ushort* xl2bf  = (ushort*)alloc((size_t)N * C * 2);
    float*  h2     = (float*)alloc((size_t)N * C * 4);

    // ---- zero barrier slots + cnt in ONE memset (they are contiguous) ----
    hipMemsetAsync(ctrs, 0, 64 * 4 + (size_t)N * 4, stream);

    // ---- CSR build (1 fused kernel, 3 barriers) ----
    setup_kernel<<<NB, 256, 0, stream>>>(row, col, cnt, dis, rowptr, cursor, adj,
                                         bsum, ctrs, N, E);

    // ---- bf16 conversions ----
    {
        int n4x = N * C / 4, n4w = IC * C / 4;
        int tot = n4x + 2 * n4w;
        f2b_all_kernel<<<(tot + 255) / 256, 256, 0, stream>>>(x, W1, W2, xbf, W1bf, W2bf, n4x, n4w);
    }

    // ---- layer 1: g1x = A_norm(x); h1 = g1x @ W1^T; bn1+relu+cast ----
    gather_bf_kernel<true><<<N, 256, 0, stream>>>(xbf, rowptr, adj, dis, g1x);
    {
        dim3 grid(IC / 128, (N + 127) / 128);
        gemm_mfma_kernel<false><<<grid, 256, 0, stream>>>(g1x, W1bf, h1, N, IC, C);
    }
    bn_fused_kernel<0><<<NB, 256, 0, stream>>>(h1, g1, b1, psum, psumsq, scale1, shift1,
                                               h1bf, nullptr, nullptr, ctrs + 8, N, IC);

    // ---- layer 2: xl2 = h1bf @ W2^T (bf16); h2 = A_norm(xl2); bn2+res+relu ----
    {
        dim3 grid(C / 128, (N + 127) / 128);
        gemm_mfma_kernel<true><<<grid, 256, 0, stream>>>(h1bf, W2bf, xl2bf, N, C, IC);
    }
    gather_bf_kernel<false><<<N, 256, 0, stream>>>(xl2bf, rowptr, adj, dis, h2);
    bn_fused_kernel<1><<<NB, 256, 0, stream>>>(h2, g2, b2, psum, psumsq, scale2, shift2,
                                               nullptr, x, out, ctrs + 12, N, C);
}

// Round 8
// 274.176 us; speedup vs baseline: 4.0583x; 4.0583x over previous
//
#include <hip/hip_runtime.h>

#define BN_EPS 1e-5f

typedef __attribute__((ext_vector_type(8))) short short8;
typedef __attribute__((ext_vector_type(4))) float floatx4;

#define GLL(gp, lp)                                                            \
    __builtin_amdgcn_global_load_lds(                                          \
        (const __attribute__((address_space(1))) void*)(gp),                   \
        (__attribute__((address_space(3))) void*)(lp), 16, 0, 0)

__device__ inline unsigned short f2bf(float f) {
    unsigned int u = __float_as_uint(f);
    unsigned int r = (u + 0x7FFF + ((u >> 16) & 1)) >> 16;  // RNE
    return (unsigned short)r;
}

__device__ inline float bf2f(unsigned short u) {
    return __uint_as_float(((unsigned int)u) << 16);
}

// Grid barrier: 1 RMW per block (arrival), last arriver sets flag (release),
// waiters spin on acquire LOADS. bar[0]=arrive, bar[1]=flag, pre-zeroed.
__device__ inline void grid_bar(int* bar, int nb) {
    __syncthreads();
    if (threadIdx.x == 0) {
        int old = __hip_atomic_fetch_add(&bar[0], 1, __ATOMIC_ACQ_REL, __HIP_MEMORY_SCOPE_AGENT);
        if (old == nb - 1) {
            __hip_atomic_store(&bar[1], 1, __ATOMIC_RELEASE, __HIP_MEMORY_SCOPE_AGENT);
        } else {
            while (!__hip_atomic_load(&bar[1], __ATOMIC_ACQUIRE, __HIP_MEMORY_SCOPE_AGENT))
                __builtin_amdgcn_s_sleep(16);
        }
    }
    __syncthreads();
}

// ---------------- fused CSR construction (1 kernel, 3 barriers) --------------
// grid = 256 blocks x 256 threads, co-resident. cnt pre-zeroed by host memset.

__global__ __launch_bounds__(256) void setup_kernel(
    const int* __restrict__ row, const int* __restrict__ col,
    int* __restrict__ cnt, float* __restrict__ dis,
    int* __restrict__ rowptr, int* __restrict__ cursor, int* __restrict__ adj,
    int* __restrict__ bsum, int* __restrict__ ctrs, int N, int E) {
    int b = blockIdx.x, t = threadIdx.x, nb = gridDim.x;
    int gid = b * 256 + t, gsz = nb * 256;

    // P1: count in-degree
    for (int e = gid; e < E; e += gsz) atomicAdd(&cnt[col[e]], 1);
    grid_bar(ctrs + 0, nb);

    // P2: dis + block-local inclusive scan of this block's node segment
    for (int i = gid; i < N; i += gsz) dis[i] = rsqrtf((float)(cnt[i] + 1));
    int per = (N + nb - 1) / nb;     // 40 for N=10000, nb=256
    int s0 = b * per;
    __shared__ int sc[256];
    __shared__ int sb[256];
    int v = (t < per && s0 + t < N) ? cnt[s0 + t] : 0;
    sc[t] = v;
    __syncthreads();
    for (int o = 1; o < 256; o <<= 1) {
        int u = (t >= o) ? sc[t - o] : 0;
        __syncthreads();
        sc[t] += u;
        __syncthreads();
    }
    if (t == 255) bsum[b] = sc[255];
    grid_bar(ctrs + 2, nb);

    // P3: every block redundantly scans the 256 block sums; write rowptr/cursor
    sb[t] = bsum[t];
    __syncthreads();
    for (int o = 1; o < 256; o <<= 1) {
        int u = (t >= o) ? sb[t - o] : 0;
        __syncthreads();
        sb[t] += u;
        __syncthreads();
    }
    int boff = (b == 0) ? 0 : sb[b - 1];
    if (t < per && s0 + t < N) {
        int ex = boff + sc[t] - v;
        rowptr[s0 + t] = ex;
        cursor[s0 + t] = ex;
    }
    if (b == 0 && t == 0) rowptr[N] = sb[255];
    grid_bar(ctrs + 4, nb);

    // P4: scatter edges into CSR
    for (int e = gid; e < E; e += gsz) {
        int pos = atomicAdd(&cursor[col[e]], 1);
        adj[pos] = row[e];
    }
}

// ---------------- fused fp32 -> bf16 conversion (x, W1, W2) ----------------

__global__ void f2b_all_kernel(const float* __restrict__ x, const float* __restrict__ W1,
                               const float* __restrict__ W2, ushort* __restrict__ xbf,
                               ushort* __restrict__ W1bf, ushort* __restrict__ W2bf,
                               int n4x, int n4w) {
    int i = blockIdx.x * blockDim.x + threadIdx.x;
    const float* src;
    ushort* dst;
    int j;
    if (i < n4x) { src = x; dst = xbf; j = i; }
    else if (i < n4x + n4w) { src = W1; dst = W1bf; j = i - n4x; }
    else if (i < n4x + 2 * n4w) { src = W2; dst = W2bf; j = i - n4x - n4w; }
    else return;
    float4 v = ((const float4*)src)[j];
    ushort4 o;
    o.x = f2bf(v.x); o.y = f2bf(v.y); o.z = f2bf(v.z); o.w = f2bf(v.w);
    ((ushort4*)dst)[j] = o;
}

// ---------------- MFMA GEMM: C[M,N] = A[M,K] @ B[N,K]^T (bf16 in) ----------

template <bool OUT_BF16>
__global__ __launch_bounds__(256) void gemm_mfma_kernel(
    const ushort* __restrict__ A, const ushort* __restrict__ B,
    void* __restrict__ Cout, int M, int N, int K) {
    __shared__ ushort As[128 * 32];
    __shared__ ushort Bs[128 * 32];
    int tid = threadIdx.x;
    int wave = tid >> 6;
    int lane = tid & 63;
    int quad = lane >> 4;
    int l15 = lane & 15;
    int m0 = blockIdx.y * 128;
    int n0 = blockIdx.x * 128;

    int srow = lane >> 2;
    int skoff = (lane & 3) * 8;

    floatx4 acc[4][4];
#pragma unroll
    for (int i = 0; i < 4; i++)
#pragma unroll
        for (int j = 0; j < 4; j++) acc[i][j] = (floatx4){0.f, 0.f, 0.f, 0.f};

    int wm = (wave & 1) * 64;
    int wn = (wave >> 1) * 64;

    for (int k0 = 0; k0 < K; k0 += 32) {
#pragma unroll
        for (int cc = 0; cc < 2; cc++) {
            int c = wave * 2 + cc;
            int arow = m0 + c * 16 + srow;
            arow = min(arow, M - 1);
            const ushort* ga = A + (size_t)arow * K + k0 + skoff;
            GLL(ga, (char*)As + c * 1024);
            int brow = n0 + c * 16 + srow;
            const ushort* gb = B + (size_t)brow * K + k0 + skoff;
            GLL(gb, (char*)Bs + c * 1024);
        }
        __syncthreads();

        short8 af[4], bfr[4];
#pragma unroll
        for (int i = 0; i < 4; i++) {
            int r = wm + i * 16 + l15;
            af[i] = *(const short8*)(As + r * 32 + quad * 8);
        }
#pragma unroll
        for (int j = 0; j < 4; j++) {
            int r = wn + j * 16 + l15;
            bfr[j] = *(const short8*)(Bs + r * 32 + quad * 8);
        }
#pragma unroll
        for (int i = 0; i < 4; i++)
#pragma unroll
            for (int j = 0; j < 4; j++)
                acc[i][j] = __builtin_amdgcn_mfma_f32_16x16x32_bf16(af[i], bfr[j], acc[i][j], 0, 0, 0);
        __syncthreads();
    }

#pragma unroll
    for (int i = 0; i < 4; i++) {
#pragma unroll
        for (int r = 0; r < 4; r++) {
            int row = m0 + wm + i * 16 + quad * 4 + r;
            if (row < M) {
                if (OUT_BF16) {
                    ushort* cp = (ushort*)Cout + (size_t)row * N + n0 + wn + l15;
#pragma unroll
                    for (int j = 0; j < 4; j++) cp[j * 16] = f2bf(acc[i][j][r]);
                } else {
                    float* cp = (float*)Cout + (size_t)row * N + n0 + wn + l15;
#pragma unroll
                    for (int j = 0; j < 4; j++) cp[j * 16] = acc[i][j][r];
                }
            }
        }
    }
}

// ---------------- bf16 gather, C=256 channels ----------------

template <bool OUT_BF16>
__global__ __launch_bounds__(256) void gather_bf_kernel(
    const ushort* __restrict__ xl, const int* __restrict__ rowptr,
    const int* __restrict__ adj, const float* __restrict__ dis,
    void* __restrict__ h) {
    int v = blockIdx.x;
    int wave = threadIdx.x >> 6;
    int lane = threadIdx.x & 63;
    float dv = dis[v];

    float acc[4] = {0.f, 0.f, 0.f, 0.f};
    int e0 = rowptr[v], e1 = rowptr[v + 1];
    for (int e = e0 + wave; e < e1; e += 4) {
        int r = adj[e];
        float wgt = dis[r] * dv;
        ushort4 u = ((const ushort4*)xl)[(size_t)r * 64 + lane];
        acc[0] = fmaf(bf2f(u.x), wgt, acc[0]);
        acc[1] = fmaf(bf2f(u.y), wgt, acc[1]);
        acc[2] = fmaf(bf2f(u.z), wgt, acc[2]);
        acc[3] = fmaf(bf2f(u.w), wgt, acc[3]);
    }

    __shared__ float4 red[4][64];
    red[wave][lane] = make_float4(acc[0], acc[1], acc[2], acc[3]);
    __syncthreads();
    if (wave == 0) {
        float4 s = red[0][lane];
        float4 b = red[1][lane];
        float4 c = red[2][lane];
        float4 d = red[3][lane];
        s.x += b.x + c.x + d.x;
        s.y += b.y + c.y + d.y;
        s.z += b.z + c.z + d.z;
        s.w += b.w + c.w + d.w;
        ushort4 u = ((const ushort4*)xl)[(size_t)v * 64 + lane];
        float w2 = dv * dv;
        s.x = fmaf(bf2f(u.x), w2, s.x);
        s.y = fmaf(bf2f(u.y), w2, s.y);
        s.z = fmaf(bf2f(u.z), w2, s.z);
        s.w = fmaf(bf2f(u.w), w2, s.w);
        if (OUT_BF16) {
            ushort4 o;
            o.x = f2bf(s.x); o.y = f2bf(s.y); o.z = f2bf(s.z); o.w = f2bf(s.w);
            ((ushort4*)h)[(size_t)v * 64 + lane] = o;
        } else {
            ((float4*)h)[(size_t)v * 64 + lane] = s;
        }
    }
}

// ---------------- batchnorm stats: two-stage, no atomics (R4-proven) --------
// Stage A: per-chunk partials, channel-major [IC][chunks].

__global__ __launch_bounds__(256) void bn_partial_kernel(
    const float* __restrict__ h, float* __restrict__ psum, float* __restrict__ psumsq,
    int N, int IC, int rows_per_chunk, int chunks) {
    int groups = IC >> 2;          // 128 (IC=512) or 64 (C=256)
    int rpi = 256 / groups;        // rows per iteration: 2 or 4
    int t = threadIdx.x;
    int g = t & (groups - 1);
    int ro = t / groups;
    int r0 = blockIdx.x * rows_per_chunk;
    int r1 = min(r0 + rows_per_chunk, N);

    float4 s = make_float4(0.f, 0.f, 0.f, 0.f);
    float4 q = make_float4(0.f, 0.f, 0.f, 0.f);
    for (int r = r0 + ro; r < r1; r += rpi) {
        float4 v = *(const float4*)(h + (size_t)r * IC + g * 4);
        s.x += v.x; s.y += v.y; s.z += v.z; s.w += v.w;
        q.x += v.x * v.x; q.y += v.y * v.y; q.z += v.z * v.z; q.w += v.w * v.w;
    }

    __shared__ float4 redS[256];
    __shared__ float4 redQ[256];
    redS[t] = s;
    redQ[t] = q;
    __syncthreads();
    if (ro == 0) {
        for (int i = 1; i < rpi; i++) {
            float4 o = redS[t + i * groups];
            s.x += o.x; s.y += o.y; s.z += o.z; s.w += o.w;
            float4 p = redQ[t + i * groups];
            q.x += p.x; q.y += p.y; q.z += p.z; q.w += p.w;
        }
        int k = blockIdx.x;
        psum[(size_t)(4 * g + 0) * chunks + k] = s.x;
        psum[(size_t)(4 * g + 1) * chunks + k] = s.y;
        psum[(size_t)(4 * g + 2) * chunks + k] = s.z;
        psum[(size_t)(4 * g + 3) * chunks + k] = s.w;
        psumsq[(size_t)(4 * g + 0) * chunks + k] = q.x;
        psumsq[(size_t)(4 * g + 1) * chunks + k] = q.y;
        psumsq[(size_t)(4 * g + 2) * chunks + k] = q.z;
        psumsq[(size_t)(4 * g + 3) * chunks + k] = q.w;
    }
}

// Stage B: one wave per channel; coalesced lane-parallel reduce -> scale/shift.
__global__ __launch_bounds__(256) void bn_reduce_kernel(
    const float* __restrict__ psum, const float* __restrict__ psumsq,
    const float* __restrict__ gamma, const float* __restrict__ beta,
    float* __restrict__ scale, float* __restrict__ shift,
    int N, int chunks) {
    int wave = threadIdx.x >> 6;
    int lane = threadIdx.x & 63;
    int c = blockIdx.x * 4 + wave;
    float s = 0.f, q = 0.f;
    for (int k = lane; k < chunks; k += 64) {
        s += psum[(size_t)c * chunks + k];
        q += psumsq[(size_t)c * chunks + k];
    }
#pragma unroll
    for (int off = 32; off > 0; off >>= 1) {
        s += __shfl_down(s, off, 64);
        q += __shfl_down(q, off, 64);
    }
    if (lane == 0) {
        float invN = 1.0f / (float)N;
        float mean = s * invN;
        float var = q * invN - mean * mean;
        float sc = gamma[c] * rsqrtf(var + BN_EPS);
        scale[c] = sc;
        shift[c] = beta[c] - mean * sc;
    }
}

// BN+ReLU applied, then convert to bf16 (feeds GEMM2's A)
__global__ void bn_apply_b_kernel(const float* __restrict__ h,
                                  const float* __restrict__ scale,
                                  const float* __restrict__ shift,
                                  ushort* __restrict__ out, int n4, int IC4) {
    int i = blockIdx.x * blockDim.x + threadIdx.x;
    if (i >= n4) return;
    int c4 = (i & (IC4 - 1)) * 4;
    float4 v = ((const float4*)h)[i];
    ushort4 o;
    o.x = f2bf(fmaxf(fmaf(v.x, scale[c4 + 0], shift[c4 + 0]), 0.f));
    o.y = f2bf(fmaxf(fmaf(v.y, scale[c4 + 1], shift[c4 + 1]), 0.f));
    o.z = f2bf(fmaxf(fmaf(v.z, scale[c4 + 2], shift[c4 + 2]), 0.f));
    o.w = f2bf(fmaxf(fmaf(v.w, scale[c4 + 3], shift[c4 + 3]), 0.f));
    ((ushort4*)out)[i] = o;
}

// ---------------- final: out = relu(bn2(h2) + x) ----------------

__global__ void final_kernel(const float* __restrict__ h2, const float* __restrict__ x,
                             const float* __restrict__ scale, const float* __restrict__ shift,
                             float* __restrict__ out, int total4, int C4) {
    int idx = blockIdx.x * blockDim.x + threadIdx.x;
    if (idx >= total4) return;
    int c4 = (idx % C4) * 4;
    float4 h = ((const float4*)h2)[idx];
    float4 xv = ((const float4*)x)[idx];
    float4 o;
    o.x = fmaxf(fmaf(h.x, scale[c4 + 0], shift[c4 + 0]) + xv.x, 0.f);
    o.y = fmaxf(fmaf(h.y, scale[c4 + 1], shift[c4 + 1]) + xv.y, 0.f);
    o.z = fmaxf(fmaf(h.z, scale[c4 + 2], shift[c4 + 2]) + xv.z, 0.f);
    o.w = fmaxf(fmaf(h.w, scale[c4 + 3], shift[c4 + 3]) + xv.w, 0.f);
    ((float4*)out)[idx] = o;
}

// ---------------- launch ----------------

extern "C" void kernel_launch(void* const* d_in, const int* in_sizes, int n_in,
                              void* d_out, int out_size, void* d_ws, size_t ws_size,
                              hipStream_t stream) {
    const float* x  = (const float*)d_in[0];
    const int*   es = (const int*)d_in[1];
    const float* W1 = (const float*)d_in[2];
    const float* g1 = (const float*)d_in[3];
    const float* b1 = (const float*)d_in[4];
    const float* W2 = (const float*)d_in[5];
    const float* g2 = (const float*)d_in[6];
    const float* b2 = (const float*)d_in[7];
    float* out = (float*)d_out;

    const int E  = in_sizes[1] / 2;
    const int IC = in_sizes[3];   // 512
    const int C  = in_sizes[7];   // 256
    const int N  = in_sizes[0] / C;
    const int NB = 256;
    const int CHUNKS = 512;

    const int* row = es;
    const int* col = es + E;

    // ---- workspace layout (ctrs + cnt first: one covering memset) ----
    char* w = (char*)d_ws;
    size_t off = 0;
    auto alloc = [&](size_t bytes) -> void* {
        void* p = w + off;
        off = (off + bytes + 255) & ~(size_t)255;
        return p;
    };
    int*   ctrs    = (int*)alloc(64 * 4);
    int*   cnt     = (int*)alloc((size_t)N * 4);
    float* dis     = (float*)alloc((size_t)N * 4);
    int*   rowptr  = (int*)alloc((size_t)(N + 1) * 4);
    int*   cursor  = (int*)alloc((size_t)N * 4);
    int*   adj     = (int*)alloc((size_t)E * 4);
    int*   bsum    = (int*)alloc((size_t)NB * 4);
    float* psum    = (float*)alloc((size_t)IC * CHUNKS * 4);
    float* psumsq  = (float*)alloc((size_t)IC * CHUNKS * 4);
    float* scale1  = (float*)alloc((size_t)IC * 4);
    float* shift1  = (float*)alloc((size_t)IC * 4);
    float* scale2  = (float*)alloc((size_t)C * 4);
    float* shift2  = (float*)alloc((size_t)C * 4);
    ushort* xbf    = (ushort*)alloc((size_t)N * C * 2);
    ushort* W1bf   = (ushort*)alloc((size_t)IC * C * 2);
    ushort* W2bf   = (ushort*)alloc((size_t)IC * C * 2);
    ushort* g1x    = (ushort*)alloc((size_t)N * C * 2);
    float*  h1     = (float*)alloc((size_t)N * IC * 4);
    ushort* h1bf   = (ushort*)alloc((size_t)N * IC * 2);
    ushort* xl2bf  = (ushort*)alloc((size_t)N * C * 2);
    float*  h2     = (float*)alloc((size_t)N * C * 4);

    // ---- zero barrier slots + cnt in ONE memset (contiguous) ----
    hipMemsetAsync(ctrs, 0, 64 * 4 + (size_t)N * 4, stream);

    // ---- CSR build (fused, 3 load-spin barriers) ----
    setup_kernel<<<NB, 256, 0, stream>>>(row, col, cnt, dis, rowptr, cursor, adj,
                                         bsum, ctrs, N, E);

    // ---- bf16 conversions ----
    {
        int n4x = N * C / 4, n4w = IC * C / 4;
        int tot = n4x + 2 * n4w;
        f2b_all_kernel<<<(tot + 255) / 256, 256, 0, stream>>>(x, W1, W2, xbf, W1bf, W2bf, n4x, n4w);
    }

    // ---- layer 1: g1x = A_norm(x); h1 = g1x @ W1^T ----
    gather_bf_kernel<true><<<N, 256, 0, stream>>>(xbf, rowptr, adj, dis, g1x);
    {
        dim3 grid(IC / 128, (N + 127) / 128);
        gemm_mfma_kernel<false><<<grid, 256, 0, stream>>>(g1x, W1bf, h1, N, IC, C);
    }
    {
        int rpc = (N + CHUNKS - 1) / CHUNKS;
        bn_partial_kernel<<<CHUNKS, 256, 0, stream>>>(h1, psum, psumsq, N, IC, rpc, CHUNKS);
        bn_reduce_kernel<<<IC / 4, 256, 0, stream>>>(psum, psumsq, g1, b1, scale1, shift1, N, CHUNKS);
    }
    bn_apply_b_kernel<<<((N * IC / 4) + 255) / 256, 256, 0, stream>>>(
        h1, scale1, shift1, h1bf, N * IC / 4, IC / 4);

    // ---- layer 2: xl2 = h1bf @ W2^T (bf16); h2 = A_norm(xl2) ----
    {
        dim3 grid(C / 128, (N + 127) / 128);
        gemm_mfma_kernel<true><<<grid, 256, 0, stream>>>(h1bf, W2bf, xl2bf, N, C, IC);
    }
    gather_bf_kernel<false><<<N, 256, 0, stream>>>(xl2bf, rowptr, adj, dis, h2);
    {
        int rpc = (N + CHUNKS - 1) / CHUNKS;
        bn_partial_kernel<<<CHUNKS, 256, 0, stream>>>(h2, psum, psumsq, N, C, rpc, CHUNKS);
        bn_reduce_kernel<<<C / 4, 256, 0, stream>>>(psum, psumsq, g2, b2, scale2, shift2, N, CHUNKS);
    }

    // ---- epilogue: relu(bn2(h2) + x) ----
    {
        int total4 = (N * C) / 4;
        final_kernel<<<(total4 + 255) / 256, 256, 0, stream>>>(h2, x, scale2, shift2, out, total4, C / 4);
    }
}

// Round 9
// 221.607 us; speedup vs baseline: 5.0210x; 1.2372x over previous
//
#include <hip/hip_runtime.h>

#define BN_EPS 1e-5f

typedef __attribute__((ext_vector_type(8))) short short8;
typedef __attribute__((ext_vector_type(4))) float floatx4;

#define GLL(gp, lp)                                                            \
    __builtin_amdgcn_global_load_lds(                                          \
        (const __attribute__((address_space(1))) void*)(gp),                   \
        (__attribute__((address_space(3))) void*)(lp), 16, 0, 0)

__device__ inline unsigned short f2bf(float f) {
    unsigned int u = __float_as_uint(f);
    unsigned int r = (u + 0x7FFF + ((u >> 16) & 1)) >> 16;  // RNE
    return (unsigned short)r;
}

__device__ inline float bf2f(unsigned short u) {
    return __uint_as_float(((unsigned int)u) << 16);
}

// ---------------- CSR construction (small unfused kernels; no grid sync) ----

__global__ void count_deg_kernel(const int* __restrict__ col, int* __restrict__ cnt, int E) {
    int e = blockIdx.x * blockDim.x + threadIdx.x;
    if (e < E) atomicAdd(&cnt[col[e]], 1);
}

// single-block scan over N counts -> rowptr/cursor; also computes dis.
__global__ __launch_bounds__(1024) void scan_dis_kernel(
    const int* __restrict__ cnt, float* __restrict__ dis,
    int* __restrict__ rowptr, int* __restrict__ cursor, int N) {
    __shared__ int sums[1024];
    int t = threadIdx.x;
    int per = (N + 1023) / 1024;
    int start = t * per;
    int local = 0;
    for (int i = 0; i < per; i++) {
        int idx = start + i;
        if (idx < N) {
            int cv = cnt[idx];
            local += cv;
            dis[idx] = rsqrtf((float)(cv + 1));   // +1 self loop
        }
    }
    sums[t] = local;
    __syncthreads();
    for (int off = 1; off < 1024; off <<= 1) {
        int v = (t >= off) ? sums[t - off] : 0;
        __syncthreads();
        sums[t] += v;
        __syncthreads();
    }
    int run = (t == 0) ? 0 : sums[t - 1];
    for (int i = 0; i < per; i++) {
        int idx = start + i;
        if (idx < N) {
            rowptr[idx] = run;
            cursor[idx] = run;
            run += cnt[idx];
        }
    }
    if (t == 0) rowptr[N] = sums[1023];
}

__global__ void scatter_kernel(const int* __restrict__ row, const int* __restrict__ col,
                               int* __restrict__ cursor, int* __restrict__ adj, int E) {
    int e = blockIdx.x * blockDim.x + threadIdx.x;
    if (e < E) {
        int pos = atomicAdd(&cursor[col[e]], 1);
        adj[pos] = row[e];
    }
}

// ---------------- fused fp32 -> bf16 conversion (x, W1, W2) ----------------

__global__ void f2b_all_kernel(const float* __restrict__ x, const float* __restrict__ W1,
                               const float* __restrict__ W2, ushort* __restrict__ xbf,
                               ushort* __restrict__ W1bf, ushort* __restrict__ W2bf,
                               int n4x, int n4w) {
    int i = blockIdx.x * blockDim.x + threadIdx.x;
    const float* src;
    ushort* dst;
    int j;
    if (i < n4x) { src = x; dst = xbf; j = i; }
    else if (i < n4x + n4w) { src = W1; dst = W1bf; j = i - n4x; }
    else if (i < n4x + 2 * n4w) { src = W2; dst = W2bf; j = i - n4x - n4w; }
    else return;
    float4 v = ((const float4*)src)[j];
    ushort4 o;
    o.x = f2bf(v.x); o.y = f2bf(v.y); o.z = f2bf(v.z); o.w = f2bf(v.w);
    ((ushort4*)dst)[j] = o;
}

// ---------------- MFMA GEMM: C[M,N] = A[M,K] @ B[N,K]^T (bf16 in) ----------
// STATS: epilogue emits per-column (channel) partial sum/sumsq of this block's
// row-tile into psum/psumsq[col][blockIdx.y] (no atomics; rows >= M masked).

template <bool OUT_BF16, bool STATS>
__global__ __launch_bounds__(256) void gemm_mfma_kernel(
    const ushort* __restrict__ A, const ushort* __restrict__ B,
    void* __restrict__ Cout, float* __restrict__ psum, float* __restrict__ psumsq,
    int chunks, int M, int N, int K) {
    __shared__ ushort As[128 * 32];
    __shared__ ushort Bs[128 * 32];
    int tid = threadIdx.x;
    int wave = tid >> 6;
    int lane = tid & 63;
    int quad = lane >> 4;
    int l15 = lane & 15;
    int m0 = blockIdx.y * 128;
    int n0 = blockIdx.x * 128;

    int srow = lane >> 2;
    int skoff = (lane & 3) * 8;

    floatx4 acc[4][4];
#pragma unroll
    for (int i = 0; i < 4; i++)
#pragma unroll
        for (int j = 0; j < 4; j++) acc[i][j] = (floatx4){0.f, 0.f, 0.f, 0.f};

    int wm = (wave & 1) * 64;
    int wn = (wave >> 1) * 64;

    for (int k0 = 0; k0 < K; k0 += 32) {
#pragma unroll
        for (int cc = 0; cc < 2; cc++) {
            int c = wave * 2 + cc;
            int arow = m0 + c * 16 + srow;
            arow = min(arow, M - 1);
            const ushort* ga = A + (size_t)arow * K + k0 + skoff;
            GLL(ga, (char*)As + c * 1024);
            int brow = n0 + c * 16 + srow;
            const ushort* gb = B + (size_t)brow * K + k0 + skoff;
            GLL(gb, (char*)Bs + c * 1024);
        }
        __syncthreads();

        short8 af[4], bfr[4];
#pragma unroll
        for (int i = 0; i < 4; i++) {
            int r = wm + i * 16 + l15;
            af[i] = *(const short8*)(As + r * 32 + quad * 8);
        }
#pragma unroll
        for (int j = 0; j < 4; j++) {
            int r = wn + j * 16 + l15;
            bfr[j] = *(const short8*)(Bs + r * 32 + quad * 8);
        }
#pragma unroll
        for (int i = 0; i < 4; i++)
#pragma unroll
            for (int j = 0; j < 4; j++)
                acc[i][j] = __builtin_amdgcn_mfma_f32_16x16x32_bf16(af[i], bfr[j], acc[i][j], 0, 0, 0);
        __syncthreads();
    }

#pragma unroll
    for (int i = 0; i < 4; i++) {
#pragma unroll
        for (int r = 0; r < 4; r++) {
            int row = m0 + wm + i * 16 + quad * 4 + r;
            if (row < M) {
                if (OUT_BF16) {
                    ushort* cp = (ushort*)Cout + (size_t)row * N + n0 + wn + l15;
#pragma unroll
                    for (int j = 0; j < 4; j++) cp[j * 16] = f2bf(acc[i][j][r]);
                } else {
                    float* cp = (float*)Cout + (size_t)row * N + n0 + wn + l15;
#pragma unroll
                    for (int j = 0; j < 4; j++) cp[j * 16] = acc[i][j][r];
                }
            }
        }
    }

    if (STATS) {
        // per-lane partials over this wave's 64-row half (masked at M)
        float s[4] = {0.f, 0.f, 0.f, 0.f};
        float q[4] = {0.f, 0.f, 0.f, 0.f};
#pragma unroll
        for (int i = 0; i < 4; i++) {
#pragma unroll
            for (int r = 0; r < 4; r++) {
                if (m0 + wm + i * 16 + quad * 4 + r < M) {
#pragma unroll
                    for (int j = 0; j < 4; j++) {
                        float v = acc[i][j][r];
                        s[j] += v;
                        q[j] += v * v;
                    }
                }
            }
        }
        // reduce across quads (lanes sharing l15)
#pragma unroll
        for (int j = 0; j < 4; j++) {
            s[j] += __shfl_xor(s[j], 16, 64);
            s[j] += __shfl_xor(s[j], 32, 64);
            q[j] += __shfl_xor(q[j], 16, 64);
            q[j] += __shfl_xor(q[j], 32, 64);
        }
        __shared__ float sArr[4][64];
        __shared__ float qArr[4][64];
        if (quad == 0) {
#pragma unroll
            for (int j = 0; j < 4; j++) {
                sArr[wave][j * 16 + l15] = s[j];
                qArr[wave][j * 16 + l15] = q[j];
            }
        }
        __syncthreads();
        // combine wave pairs: waves {0,1} -> cols [0,64), {2,3} -> [64,128)
        if (tid < 128) {
            int half = tid >> 6;
            int cc = tid & 63;
            float ss = sArr[half * 2][cc] + sArr[half * 2 + 1][cc];
            float qq = qArr[half * 2][cc] + qArr[half * 2 + 1][cc];
            int col = n0 + half * 64 + cc;
            psum[(size_t)col * chunks + blockIdx.y] = ss;
            psumsq[(size_t)col * chunks + blockIdx.y] = qq;
        }
    }
}

// ---------------- bf16 gather, C=256 channels ----------------

template <bool OUT_BF16>
__global__ __launch_bounds__(256) void gather_bf_kernel(
    const ushort* __restrict__ xl, const int* __restrict__ rowptr,
    const int* __restrict__ adj, const float* __restrict__ dis,
    void* __restrict__ h) {
    int v = blockIdx.x;
    int wave = threadIdx.x >> 6;
    int lane = threadIdx.x & 63;
    float dv = dis[v];

    float acc[4] = {0.f, 0.f, 0.f, 0.f};
    int e0 = rowptr[v], e1 = rowptr[v + 1];
    for (int e = e0 + wave; e < e1; e += 4) {
        int r = adj[e];
        float wgt = dis[r] * dv;
        ushort4 u = ((const ushort4*)xl)[(size_t)r * 64 + lane];
        acc[0] = fmaf(bf2f(u.x), wgt, acc[0]);
        acc[1] = fmaf(bf2f(u.y), wgt, acc[1]);
        acc[2] = fmaf(bf2f(u.z), wgt, acc[2]);
        acc[3] = fmaf(bf2f(u.w), wgt, acc[3]);
    }

    __shared__ float4 red[4][64];
    red[wave][lane] = make_float4(acc[0], acc[1], acc[2], acc[3]);
    __syncthreads();
    if (wave == 0) {
        float4 s = red[0][lane];
        float4 b = red[1][lane];
        float4 c = red[2][lane];
        float4 d = red[3][lane];
        s.x += b.x + c.x + d.x;
        s.y += b.y + c.y + d.y;
        s.z += b.z + c.z + d.z;
        s.w += b.w + c.w + d.w;
        ushort4 u = ((const ushort4*)xl)[(size_t)v * 64 + lane];
        float w2 = dv * dv;
        s.x = fmaf(bf2f(u.x), w2, s.x);
        s.y = fmaf(bf2f(u.y), w2, s.y);
        s.z = fmaf(bf2f(u.z), w2, s.z);
        s.w = fmaf(bf2f(u.w), w2, s.w);
        if (OUT_BF16) {
            ushort4 o;
            o.x = f2bf(s.x); o.y = f2bf(s.y); o.z = f2bf(s.z); o.w = f2bf(s.w);
            ((ushort4*)h)[(size_t)v * 64 + lane] = o;
        } else {
            ((float4*)h)[(size_t)v * 64 + lane] = s;
        }
    }
}

// ---------------- batchnorm stats (layer 2): two-stage, no atomics ----------

__global__ __launch_bounds__(256) void bn_partial_kernel(
    const float* __restrict__ h, float* __restrict__ psum, float* __restrict__ psumsq,
    int N, int IC, int rows_per_chunk, int chunks) {
    int groups = IC >> 2;
    int rpi = 256 / groups;
    int t = threadIdx.x;
    int g = t & (groups - 1);
    int ro = t / groups;
    int r0 = blockIdx.x * rows_per_chunk;
    int r1 = min(r0 + rows_per_chunk, N);

    float4 s = make_float4(0.f, 0.f, 0.f, 0.f);
    float4 q = make_float4(0.f, 0.f, 0.f, 0.f);
    for (int r = r0 + ro; r < r1; r += rpi) {
        float4 v = *(const float4*)(h + (size_t)r * IC + g * 4);
        s.x += v.x; s.y += v.y; s.z += v.z; s.w += v.w;
        q.x += v.x * v.x; q.y += v.y * v.y; q.z += v.z * v.z; q.w += v.w * v.w;
    }

    __shared__ float4 redS[256];
    __shared__ float4 redQ[256];
    redS[t] = s;
    redQ[t] = q;
    __syncthreads();
    if (ro == 0) {
        for (int i = 1; i < rpi; i++) {
            float4 o = redS[t + i * groups];
            s.x += o.x; s.y += o.y; s.z += o.z; s.w += o.w;
            float4 p = redQ[t + i * groups];
            q.x += p.x; q.y += p.y; q.z += p.z; q.w += p.w;
        }
        int k = blockIdx.x;
        psum[(size_t)(4 * g + 0) * chunks + k] = s.x;
        psum[(size_t)(4 * g + 1) * chunks + k] = s.y;
        psum[(size_t)(4 * g + 2) * chunks + k] = s.z;
        psum[(size_t)(4 * g + 3) * chunks + k] = s.w;
        psumsq[(size_t)(4 * g + 0) * chunks + k] = q.x;
        psumsq[(size_t)(4 * g + 1) * chunks + k] = q.y;
        psumsq[(size_t)(4 * g + 2) * chunks + k] = q.z;
        psumsq[(size_t)(4 * g + 3) * chunks + k] = q.w;
    }
}

// one wave per channel; coalesced lane-parallel reduce -> scale/shift.
__global__ __launch_bounds__(256) void bn_reduce_kernel(
    const float* __restrict__ psum, const float* __restrict__ psumsq,
    const float* __restrict__ gamma, const float* __restrict__ beta,
    float* __restrict__ scale, float* __restrict__ shift,
    int N, int chunks) {
    int wave = threadIdx.x >> 6;
    int lane = threadIdx.x & 63;
    int c = blockIdx.x * 4 + wave;
    float s = 0.f, q = 0.f;
    for (int k = lane; k < chunks; k += 64) {
        s += psum[(size_t)c * chunks + k];
        q += psumsq[(size_t)c * chunks + k];
    }
#pragma unroll
    for (int off = 32; off > 0; off >>= 1) {
        s += __shfl_down(s, off, 64);
        q += __shfl_down(q, off, 64);
    }
    if (lane == 0) {
        float invN = 1.0f / (float)N;
        float mean = s * invN;
        float var = q * invN - mean * mean;
        float sc = gamma[c] * rsqrtf(var + BN_EPS);
        scale[c] = sc;
        shift[c] = beta[c] - mean * sc;
    }
}

// BN+ReLU applied, then convert to bf16 (feeds GEMM2's A)
__global__ void bn_apply_b_kernel(const float* __restrict__ h,
                                  const float* __restrict__ scale,
                                  const float* __restrict__ shift,
                                  ushort* __restrict__ out, int n4, int IC4) {
    int i = blockIdx.x * blockDim.x + threadIdx.x;
    if (i >= n4) return;
    int c4 = (i & (IC4 - 1)) * 4;
    float4 v = ((const float4*)h)[i];
    ushort4 o;
    o.x = f2bf(fmaxf(fmaf(v.x, scale[c4 + 0], shift[c4 + 0]), 0.f));
    o.y = f2bf(fmaxf(fmaf(v.y, scale[c4 + 1], shift[c4 + 1]), 0.f));
    o.z = f2bf(fmaxf(fmaf(v.z, scale[c4 + 2], shift[c4 + 2]), 0.f));
    o.w = f2bf(fmaxf(fmaf(v.w, scale[c4 + 3], shift[c4 + 3]), 0.f));
    ((ushort4*)out)[i] = o;
}

// ---------------- final: out = relu(bn2(h2) + x) ----------------

__global__ void final_kernel(const float* __restrict__ h2, const float* __restrict__ x,
                             const float* __restrict__ scale, const float* __restrict__ shift,
                             float* __restrict__ out, int total4, int C4) {
    int idx = blockIdx.x * blockDim.x + threadIdx.x;
    if (idx >= total4) return;
    int c4 = (idx % C4) * 4;
    float4 h = ((const float4*)h2)[idx];
    float4 xv = ((const float4*)x)[idx];
    float4 o;
    o.x = fmaxf(fmaf(h.x, scale[c4 + 0], shift[c4 + 0]) + xv.x, 0.f);
    o.y = fmaxf(fmaf(h.y, scale[c4 + 1], shift[c4 + 1]) + xv.y, 0.f);
    o.z = fmaxf(fmaf(h.z, scale[c4 + 2], shift[c4 + 2]) + xv.z, 0.f);
    o.w = fmaxf(fmaf(h.w, scale[c4 + 3], shift[c4 + 3]) + xv.w, 0.f);
    ((float4*)out)[idx] = o;
}

// ---------------- launch ----------------

extern "C" void kernel_launch(void* const* d_in, const int* in_sizes, int n_in,
                              void* d_out, int out_size, void* d_ws, size_t ws_size,
                              hipStream_t stream) {
    const float* x  = (const float*)d_in[0];
    const int*   es = (const int*)d_in[1];
    const float* W1 = (const float*)d_in[2];
    const float* g1 = (const float*)d_in[3];
    const float* b1 = (const float*)d_in[4];
    const float* W2 = (const float*)d_in[5];
    const float* g2 = (const float*)d_in[6];
    const float* b2 = (const float*)d_in[7];
    float* out = (float*)d_out;

    const int E  = in_sizes[1] / 2;
    const int IC = in_sizes[3];   // 512
    const int C  = in_sizes[7];   // 256
    const int N  = in_sizes[0] / C;
    const int CHUNKS = 512;
    const int MTILES = (N + 127) / 128;   // 79: chunks for GEMM1-fused stats

    const int* row = es;
    const int* col = es + E;

    // ---- workspace layout (cnt first: single memset) ----
    char* w = (char*)d_ws;
    size_t off = 0;
    auto alloc = [&](size_t bytes) -> void* {
        void* p = w + off;
        off = (off + bytes + 255) & ~(size_t)255;
        return p;
    };
    int*   cnt     = (int*)alloc((size_t)N * 4);
    float* dis     = (float*)alloc((size_t)N * 4);
    int*   rowptr  = (int*)alloc((size_t)(N + 1) * 4);
    int*   cursor  = (int*)alloc((size_t)N * 4);
    int*   adj     = (int*)alloc((size_t)E * 4);
    float* psum    = (float*)alloc((size_t)IC * CHUNKS * 4);
    float* psumsq  = (float*)alloc((size_t)IC * CHUNKS * 4);
    float* scale1  = (float*)alloc((size_t)IC * 4);
    float* shift1  = (float*)alloc((size_t)IC * 4);
    float* scale2  = (float*)alloc((size_t)C * 4);
    float* shift2  = (float*)alloc((size_t)C * 4);
    ushort* xbf    = (ushort*)alloc((size_t)N * C * 2);
    ushort* W1bf   = (ushort*)alloc((size_t)IC * C * 2);
    ushort* W2bf   = (ushort*)alloc((size_t)IC * C * 2);
    ushort* g1x    = (ushort*)alloc((size_t)N * C * 2);
    float*  h1     = (float*)alloc((size_t)N * IC * 4);
    ushort* h1bf   = (ushort*)alloc((size_t)N * IC * 2);
    ushort* xl2bf  = (ushort*)alloc((size_t)N * C * 2);
    float*  h2     = (float*)alloc((size_t)N * C * 4);

    hipMemsetAsync(cnt, 0, (size_t)N * 4, stream);

    // ---- CSR build ----
    count_deg_kernel<<<(E + 255) / 256, 256, 0, stream>>>(col, cnt, E);
    scan_dis_kernel<<<1, 1024, 0, stream>>>(cnt, dis, rowptr, cursor, N);
    scatter_kernel<<<(E + 255) / 256, 256, 0, stream>>>(row, col, cursor, adj, E);

    // ---- bf16 conversions ----
    {
        int n4x = N * C / 4, n4w = IC * C / 4;
        int tot = n4x + 2 * n4w;
        f2b_all_kernel<<<(tot + 255) / 256, 256, 0, stream>>>(x, W1, W2, xbf, W1bf, W2bf, n4x, n4w);
    }

    // ---- layer 1: g1x = A_norm(x); h1 = g1x @ W1^T (+fused BN1 partials) ----
    gather_bf_kernel<true><<<N, 256, 0, stream>>>(xbf, rowptr, adj, dis, g1x);
    {
        dim3 grid(IC / 128, MTILES);
        gemm_mfma_kernel<false, true><<<grid, 256, 0, stream>>>(
            g1x, W1bf, h1, psum, psumsq, MTILES, N, IC, C);
    }
    bn_reduce_kernel<<<IC / 4, 256, 0, stream>>>(psum, psumsq, g1, b1, scale1, shift1, N, MTILES);
    bn_apply_b_kernel<<<((N * IC / 4) + 255) / 256, 256, 0, stream>>>(
        h1, scale1, shift1, h1bf, N * IC / 4, IC / 4);

    // ---- layer 2: xl2 = h1bf @ W2^T (bf16); h2 = A_norm(xl2) ----
    {
        dim3 grid(C / 128, MTILES);
        gemm_mfma_kernel<true, false><<<grid, 256, 0, stream>>>(
            h1bf, W2bf, xl2bf, nullptr, nullptr, 0, N, C, IC);
    }
    gather_bf_kernel<false><<<N, 256, 0, stream>>>(xl2bf, rowptr, adj, dis, h2);
    {
        int rpc = (N + CHUNKS - 1) / CHUNKS;
        bn_partial_kernel<<<CHUNKS, 256, 0, stream>>>(h2, psum, psumsq, N, C, rpc, CHUNKS);
        bn_reduce_kernel<<<C / 4, 256, 0, stream>>>(psum, psumsq, g2, b2, scale2, shift2, N, CHUNKS);
    }

    // ---- epilogue: relu(bn2(h2) + x) ----
    {
        int total4 = (N * C) / 4;
        final_kernel<<<(total4 + 255) / 256, 256, 0, stream>>>(h2, x, scale2, shift2, out, total4, C / 4);
    }
}